// Round 2
// baseline (48.798 us; speedup 1.0000x reference)
//
#include <hip/hip_runtime.h>

__device__ __forceinline__ float lrelu(float v) { return v >= 0.f ? v : 0.01f * v; }

// One block (256 threads) per batch element. Fully fused VAE forward. f32 in/out.
__global__ __launch_bounds__(256) void vae_fused_kernel(
    const float* __restrict__ x,
    const float* __restrict__ eps,
    const float* __restrict__ emb,
    const float* __restrict__ w_e0, const float* __restrict__ b_e0,
    const float* __restrict__ w_e1, const float* __restrict__ b_e1,
    const float* __restrict__ w_mu, const float* __restrict__ b_mu,
    const float* __restrict__ w_lv, const float* __restrict__ b_lv,
    const float* __restrict__ w_d,  const float* __restrict__ b_d,
    const float* __restrict__ w_d0, const float* __restrict__ b_d0,
    const float* __restrict__ w_d1, const float* __restrict__ b_d1,
    const float* __restrict__ w_d2, const float* __restrict__ b_d2,
    float* __restrict__ out)
{
    const int b   = blockIdx.x;
    const int tid = threadIdx.x;

    __shared__ float h1s[50];
    __shared__ float zbuf[2][64];        // [0]=z_e, [1]=z_q
    __shared__ unsigned long long rkey[256];
    __shared__ float t0s[2][100];
    __shared__ float t1s[2][60];
    __shared__ float t2s[2][30];

    // ---------------- encode ----------------
    const float xv = x[b];
    if (tid < 50) {
        float acc = b_e1[tid];
        #pragma unroll
        for (int i = 0; i < 10; ++i) {
            float h = lrelu(fmaf(xv, w_e0[i], b_e0[i]));
            acc = fmaf(h, w_e1[i * 50 + tid], acc);
        }
        h1s[tid] = lrelu(acc);
    }
    __syncthreads();
    if (tid < 64) {
        float mu = b_mu[tid];
        float lv = b_lv[tid];
        for (int i = 0; i < 50; ++i) {
            float h = h1s[i];
            mu = fmaf(h, w_mu[i * 64 + tid], mu);
            lv = fmaf(h, w_lv[i * 64 + tid], lv);
        }
        float z = fmaf(eps[b * 64 + tid], expf(0.5f * lv), mu);
        zbuf[0][tid] = z;
        out[b * 64 + tid] = z;                            // z_e
    }
    __syncthreads();

    // ---------------- SOM argmin over 4096 cells ----------------
    float zr[64];
    #pragma unroll
    for (int i = 0; i < 64; ++i) zr[i] = zbuf[0][i];

    unsigned long long bestKey = ~0ull;
    for (int it = 0; it < 16; ++it) {
        const int e = tid + it * 256;                     // consecutive lanes -> consecutive rows
        const float4* rp = reinterpret_cast<const float4*>(emb + e * 64);
        float acc = 0.f;
        #pragma unroll
        for (int c = 0; c < 16; ++c) {
            float4 v = rp[c];
            float d0 = v.x - zr[c * 4 + 0];
            float d1 = v.y - zr[c * 4 + 1];
            float d2 = v.z - zr[c * 4 + 2];
            float d3 = v.w - zr[c * 4 + 3];
            acc = fmaf(d0, d0, acc);
            acc = fmaf(d1, d1, acc);
            acc = fmaf(d2, d2, acc);
            acc = fmaf(d3, d3, acc);
        }
        // dist >= 0 so float bit pattern is order-preserving; low 32 = index
        // gives "first occurrence" tie-break like jnp.argmin.
        unsigned long long key =
            ((unsigned long long)__float_as_uint(acc) << 32) | (unsigned)e;
        bestKey = key < bestKey ? key : bestKey;
    }
    rkey[tid] = bestKey;
    __syncthreads();
    #pragma unroll
    for (int s = 128; s > 0; s >>= 1) {
        if (tid < s) {
            unsigned long long o = rkey[tid + s];
            if (o < rkey[tid]) rkey[tid] = o;
        }
        __syncthreads();
    }
    const int nmin = (int)(rkey[0] & 0xffffffffu);
    const int nx = nmin >> 6, ny = nmin & 63;

    // ---------------- z_q + neighbors ----------------
    if (tid < 64) {
        const int j = tid;
        float zq = emb[nmin * 64 + j];
        zbuf[1][j] = zq;
        out[16384 + b * 64 + j] = zq;                     // z_q
        const int nb = 32768 + b * 320;                   // z_q_neighbors [B,5,64]
        out[nb + j] = zq;                                 // row 0: z_q
        float up = (nx < 63) ? emb[((nx + 1) * 64 + ny) * 64 + j] : 0.f;
        out[nb + 64 + j] = up;                            // row 1: up
        float dn = (nx > 0) ? emb[((nx - 1) * 64 + ny) * 64 + j] : 0.f;
        out[nb + 128 + j] = dn;                           // row 2: down
        out[nb + 192 + j] = 0.f;                          // row 3: right (faithful bug: zeros)
        float lf = (ny > 0) ? emb[(nx * 64 + (ny - 1)) * 64 + j] : 0.f;
        out[nb + 256 + j] = lf;                           // row 4: left
    }
    __syncthreads();

    // ---------------- decode: wave 0 -> z_e, wave 1 -> z_q ----------------
    const int w    = tid >> 6;
    const int lane = tid & 63;
    if (w < 2) {
        for (int j = lane; j < 100; j += 64) {
            float acc = b_d[j];
            for (int i = 0; i < 64; ++i)
                acc = fmaf(zbuf[w][i], w_d[i * 100 + j], acc);
            t0s[w][j] = lrelu(acc);
        }
    }
    __syncthreads();
    if (w < 2 && lane < 60) {
        float acc = b_d0[lane];
        for (int i = 0; i < 100; ++i)
            acc = fmaf(t0s[w][i], w_d0[i * 60 + lane], acc);
        t1s[w][lane] = lrelu(acc);
    }
    __syncthreads();
    if (w < 2 && lane < 30) {
        float acc = b_d1[lane];
        for (int i = 0; i < 60; ++i)
            acc = fmaf(t1s[w][i], w_d1[i * 30 + lane], acc);
        t2s[w][lane] = lrelu(acc);
    }
    __syncthreads();
    if (w < 2 && lane == 0) {
        float acc = b_d2[0];
        for (int i = 0; i < 30; ++i)
            acc = fmaf(t2s[w][i], w_d2[i], acc);
        float r = lrelu(acc);
        // decoder_e at 114688, decoder_q at 114944
        out[(w == 0 ? 114688 : 114944) + b] = r;
    }
}

extern "C" void kernel_launch(void* const* d_in, const int* in_sizes, int n_in,
                              void* d_out, int out_size, void* d_ws, size_t ws_size,
                              hipStream_t stream) {
    (void)in_sizes; (void)n_in; (void)d_ws; (void)ws_size; (void)out_size;
    const float* x    = (const float*)d_in[0];
    const float* eps  = (const float*)d_in[1];
    const float* emb  = (const float*)d_in[2];
    const float* w_e0 = (const float*)d_in[3];
    const float* b_e0 = (const float*)d_in[4];
    const float* w_e1 = (const float*)d_in[5];
    const float* b_e1 = (const float*)d_in[6];
    const float* w_mu = (const float*)d_in[7];
    const float* b_mu = (const float*)d_in[8];
    const float* w_lv = (const float*)d_in[9];
    const float* b_lv = (const float*)d_in[10];
    const float* w_d  = (const float*)d_in[11];
    const float* b_d  = (const float*)d_in[12];
    const float* w_d0 = (const float*)d_in[13];
    const float* b_d0 = (const float*)d_in[14];
    const float* w_d1 = (const float*)d_in[15];
    const float* b_d1 = (const float*)d_in[16];
    const float* w_d2 = (const float*)d_in[17];
    const float* b_d2 = (const float*)d_in[18];
    float* out = (float*)d_out;

    vae_fused_kernel<<<256, 256, 0, stream>>>(
        x, eps, emb, w_e0, b_e0, w_e1, b_e1, w_mu, b_mu, w_lv, b_lv,
        w_d, b_d, w_d0, b_d0, w_d1, b_d1, w_d2, b_d2, out);
}